// Round 15
// baseline (217.037 us; speedup 1.0000x reference)
//
#include <hip/hip_runtime.h>
#include <hip/hip_fp16.h>
#include <math.h>

#define NN 50000
#define IND 128
#define NH 4
#define NE 800000
#define NT 3
#define NSLOPE 0.2f

#define TILE 48                    // dsts per bucket
#define NBPT 1042                  // ceil(NN/TILE)
#define NBTOT (NT * NBPT)          // 3126
#define BCAP 960                   // slots per bucket (mean 768, +6.9 sigma)
#define SRTCAP (BCAP + 3 * TILE)   // 1104: sorted + per-dst pad-to-4 dummies
#define DUMMY 0xFFFFu

#define SEB 32768                       // edges per scatter block
#define SCB ((NT * NE + SEB - 1) / SEB) // 74 scatter blocks
#define GXB ((NN + 127) / 128)          // 391 gemm blocks per type

typedef _Float16 f16x8 __attribute__((ext_vector_type(8)));
typedef float    f32x4 __attribute__((ext_vector_type(4)));

__device__ __forceinline__ unsigned pk_add_f16(unsigned a, unsigned b) {
    __half2 x = *reinterpret_cast<__half2*>(&a);
    __half2 y = *reinterpret_cast<__half2*>(&b);
    __half2 r = __hadd2(x, y);
    return *reinterpret_cast<unsigned*>(&r);
}

// ---------------- prep: W^T fp16 + gcursor init ----------------
__global__ __launch_bounds__(256) void prep_kernel(
    const float* __restrict__ W, __half* __restrict__ wt16g, int* __restrict__ gcursor)
{
    int idx = blockIdx.x * 256 + threadIdx.x;
    if (idx < NT * IND * IND) {
        int t = idx / (IND * IND), r = idx - t * (IND * IND);
        int k = r >> 7, c = r & 127;
        wt16g[((size_t)t * IND + c) * IND + k] = (__half)W[idx];   // wt16g[t][c][k]
    }
    if (idx < NBTOT) gcursor[idx] = idx * BCAP;
}

// ---------------- combined: bucket_scatter (blocks 0..SCB-1) + MFMA GEMM ----------------
__global__ __launch_bounds__(512) void scatter_gemm_kernel(
    const int* __restrict__ edges, int* __restrict__ gcursor, unsigned* __restrict__ bucketed,
    const float* __restrict__ x, const __half* __restrict__ wt16g,
    const float* __restrict__ asrc, const float* __restrict__ adst,
    __half* __restrict__ h16, float* __restrict__ es, float* __restrict__ ed)
{
    __shared__ __align__(16) char ldsbuf[34816];
    const int tid = threadIdx.x;

    if (blockIdx.x < SCB) {
        // ---- bucket scatter: SEB edges/block ----
        int* cnt = (int*)ldsbuf;                 // NBTOT ints
        int* bas = cnt + NBTOT;                  // NBTOT ints (25.0 KB total)
        for (int i = tid; i < NBTOT; i += 512) cnt[i] = 0;
        __syncthreads();
        const long long gtot = (long long)NT * NE;
        const long long g0 = (long long)blockIdx.x * SEB;
        long long g1 = g0 + SEB; if (g1 > gtot) g1 = gtot;
        for (long long g = g0 + tid; g < g1; g += 512) {
            int t = (g >= 2LL * NE) ? 2 : (g >= NE ? 1 : 0);
            int e = (int)(g - (long long)t * NE);
            int d = edges[(size_t)t * 2 * NE + NE + e];
            atomicAdd(&cnt[t * NBPT + d / TILE], 1);
        }
        __syncthreads();
        for (int i = tid; i < NBTOT; i += 512) {
            int c = cnt[i];
            bas[i] = c ? atomicAdd(&gcursor[i], c) : 0;
            cnt[i] = 0;
        }
        __syncthreads();
        for (long long g = g0 + tid; g < g1; g += 512) {
            int t = (g >= 2LL * NE) ? 2 : (g >= NE ? 1 : 0);
            int e = (int)(g - (long long)t * NE);
            const int* eb = edges + (size_t)t * 2 * NE;
            int s = eb[e], d = eb[NE + e];
            int bkt = d / TILE;
            int bg = t * NBPT + bkt;
            int pos = bas[bg] + atomicAdd(&cnt[bg], 1);
            bucketed[pos] = (unsigned)s | ((unsigned)(d - bkt * TILE) << 16);
        }
        return;
    }

    // ---- MFMA GEMM: 8 waves x 16 rows = 128 rows/block ----
    const int bx = blockIdx.x - SCB;
    const int t  = bx / GXB;
    const int gx = bx - t * GXB;
    __half* tile = (__half*)ldsbuf;
    const int wid = tid >> 6, lane = tid & 63;
    __half* tl = tile + wid * (16 * 136);
    const int l15 = lane & 15, l4 = lane >> 4;
    const int r0 = gx * 128 + wid * 16;
    if (r0 >= NN) return;                    // NN%16==0 -> wave-uniform

    const __half* wt = wt16g + (size_t)t * IND * IND;
    const float* xrow = x + (size_t)(r0 + l15) * IND;

    f32x4 acc[8];
    #pragma unroll
    for (int i = 0; i < 8; i++) acc[i] = (f32x4){0.f, 0.f, 0.f, 0.f};

    #pragma unroll
    for (int ks = 0; ks < 4; ks++) {
        const int kb = ks * 32 + l4 * 8;
        float4 x0 = *reinterpret_cast<const float4*>(xrow + kb);
        float4 x1 = *reinterpret_cast<const float4*>(xrow + kb + 4);
        f16x8 af;
        af[0] = (_Float16)x0.x; af[1] = (_Float16)x0.y;
        af[2] = (_Float16)x0.z; af[3] = (_Float16)x0.w;
        af[4] = (_Float16)x1.x; af[5] = (_Float16)x1.y;
        af[6] = (_Float16)x1.z; af[7] = (_Float16)x1.w;
        #pragma unroll
        for (int ct = 0; ct < 8; ct++) {
            f16x8 bf = *reinterpret_cast<const f16x8*>(wt + (size_t)(ct * 16 + l15) * IND + kb);
            acc[ct] = __builtin_amdgcn_mfma_f32_16x16x32_f16(af, bf, acc[ct], 0, 0, 0);
        }
    }

    #pragma unroll
    for (int ct = 0; ct < 8; ct++)
        #pragma unroll
        for (int r = 0; r < 4; r++)
            tl[(l4 * 4 + r) * 136 + ct * 16 + l15] = (__half)acc[ct][r];
    __syncthreads();

    {
        #pragma unroll
        for (int i = 0; i < 4; i++) {        // 256 x 16B chunks: full 16x128 tile
            int c = lane + 64 * i;
            int row = c >> 4, off = (c & 15) * 8;
            f16x8 v = *reinterpret_cast<const f16x8*>(tl + row * 136 + off);
            *reinterpret_cast<f16x8*>(h16 + ((size_t)t * NN + r0 + row) * IND + off) = v;
        }
        int row16 = lane >> 2, head = lane & 3;
        const __half* hr = tl + row16 * 136 + head * 32;
        const float* av = asrc + ((size_t)t * NH + head) * 32;
        const float* bv = adst + ((size_t)t * NH + head) * 32;
        float se = 0.f, de = 0.f;
        #pragma unroll
        for (int jj = 0; jj < 4; jj++) {
            f16x8 hv = *reinterpret_cast<const f16x8*>(hr + jj * 8);
            #pragma unroll
            for (int j = 0; j < 8; j++) {
                float hf = (float)hv[j];
                se = fmaf(hf, av[jj * 8 + j], se);
                de = fmaf(hf, bv[jj * 8 + j], de);
            }
        }
        int n = r0 + row16;
        es[((size_t)t * NN + n) * NH + head] = se;
        ed[((size_t)t * NN + n) * NH + head] = de;
    }
}

// ---------------- per-bucket: LDS sort (pad-to-4 w/ DUMMY) -> fused GAT ----------------
// 512 thr = 8 waves; wave w handles dsts w*6..w*6+5. Inner: quarter-wave 4-edge steps,
// GUARD-FREE (lists padded to x4; sentinel edges carry w=0, sv=0). Packed f16 accum.
// Shuffles UNCONDITIONAL (exec-mask rule).
__global__ __launch_bounds__(512) void gat_bucket_kernel(
    const unsigned* __restrict__ bucketed, const int* __restrict__ gcursor,
    const float* __restrict__ es, const float* __restrict__ ed,
    const __half* __restrict__ h16, float* __restrict__ out)
{
    __shared__ unsigned pk[BCAP];
    __shared__ unsigned srt[SRTCAP];
    __shared__ int hist[64], scn[64], cur[64];
    const int bg = blockIdx.x;
    const int t = bg / NBPT;
    const int node0 = (bg - t * NBPT) * TILE;
    const int tid = threadIdx.x;
    const int base = bg * BCAP;
    const int cnt = gcursor[bg] - base;

    if (tid < 64) { hist[tid] = 0; cur[tid] = 0; }
    __syncthreads();
    for (int i = tid; i < cnt; i += 512) {
        unsigned v = __builtin_nontemporal_load(&bucketed[base + i]);
        pk[i] = v;
        atomicAdd(&hist[(v >> 16) & 63u], 1);
    }
    __syncthreads();
    if (tid < 64) {                        // exclusive scan over PADDED counts
        int v = hist[tid];
        int v4 = (v + 3) & ~3;
        int inc = v4;
        #pragma unroll
        for (int off = 1; off < 64; off <<= 1) {
            int n = __shfl_up(inc, off, 64);
            if (tid >= off) inc += n;
        }
        scn[tid] = inc - v4;
    }
    __syncthreads();
    for (int i = tid; i < cnt; i += 512) {
        unsigned v = pk[i];
        int dl = (int)((v >> 16) & 63u);
        int pos = scn[dl] + atomicAdd(&cur[dl], 1);
        srt[pos] = v & 0xFFFFu;
    }
    if (tid < 64) {                        // pad each dst run to x4 with DUMMY
        int h = hist[tid], h4 = (h + 3) & ~3, b = scn[tid];
        for (int i = h; i < h4; i++) srt[b + i] = DUMMY;
    }
    __syncthreads();

    const int wid = tid >> 6, lane = tid & 63;
    const int el2 = lane >> 4;         // quarter index: edge offset within 4-edge step
    const int dl3 = lane & 15;         // dims 8*dl3 .. 8*dl3+7
    const int hsel = dl3 >> 2;         // head of this lane's dims
    const float* es_t = es + (size_t)t * NN * NH;
    const __half* h16_t = h16 + (size_t)t * NN * IND;

    for (int j = 0; j < 6; j++) {
        const int dloc = wid * 6 + j;
        const int node = node0 + dloc;
        if (node >= NN) break;
        const int beg = scn[dloc];
        const int nE = (hist[dloc] + 3) & ~3;      // padded count
        const float edv = ed[((size_t)t * NN + node) * NH + (lane & 3)];

        unsigned p0 = 0u, p1 = 0u, p2 = 0u, p3 = 0u;   // packed f16 accum (8 dims)
        float dsum = 0.f;

        for (int b2 = 0; b2 < nE; b2 += 16) {
            int ne = nE - b2; if (ne > 16) ne = 16;    // multiple of 4
            const int ei = lane >> 2;
            int sv = 0; unsigned wpk = 0u;
            if (ei < ne) {
                unsigned svr = srt[beg + b2 + ei];
                if (svr != DUMMY) {
                    float s = es_t[(svr << 2) + (lane & 3)] + edv;
                    s = s > 0.f ? s : NSLOPE * s;
                    float wv = __expf(s);
                    dsum += wv;
                    __half2 w2 = __float2half2_rn(wv);
                    wpk = *reinterpret_cast<unsigned*>(&w2);
                    sv = (int)svr;
                }
            }
            for (int kk = 0; kk < ne; kk += 4) {       // GUARD-FREE steps
                int sl = (kk + el2) << 2;
                int      sb = __shfl(sv, sl, 64);
                unsigned wb = (unsigned)__shfl((int)wpk, sl | hsel, 64);
                uint4 hv = *reinterpret_cast<const uint4*>(h16_t + ((size_t)sb << 7) + (dl3 << 3));
                asm("v_pk_fma_f16 %0, %1, %2, %0" : "+v"(p0) : "v"(hv.x), "v"(wb));
                asm("v_pk_fma_f16 %0, %1, %2, %0" : "+v"(p1) : "v"(hv.y), "v"(wb));
                asm("v_pk_fma_f16 %0, %1, %2, %0" : "+v"(p2) : "v"(hv.z), "v"(wb));
                asm("v_pk_fma_f16 %0, %1, %2, %0" : "+v"(p3) : "v"(hv.w), "v"(wb));
            }
        }

        // dsum: sum over edge-slots (bits 2..5), head = lane&3
        #pragma unroll
        for (int m = 4; m <= 32; m <<= 1) dsum += __shfl_xor(dsum, m, 64);
        // acc: packed f16 adds across quarters (same dl3)
        #pragma unroll
        for (int m = 16; m <= 32; m <<= 1) {
            p0 = pk_add_f16(p0, (unsigned)__shfl_xor((int)p0, m, 64));
            p1 = pk_add_f16(p1, (unsigned)__shfl_xor((int)p1, m, 64));
            p2 = pk_add_f16(p2, (unsigned)__shfl_xor((int)p2, m, 64));
            p3 = pk_add_f16(p3, (unsigned)__shfl_xor((int)p3, m, 64));
        }
        float dn = __shfl(dsum, hsel, 64) + 1e-9f;

        if (el2 == 0) {
            float rn = 1.f / dn;
            float2 f0 = __half22float2(*reinterpret_cast<__half2*>(&p0));
            float2 f1 = __half22float2(*reinterpret_cast<__half2*>(&p1));
            float2 f2 = __half22float2(*reinterpret_cast<__half2*>(&p2));
            float2 f3 = __half22float2(*reinterpret_cast<__half2*>(&p3));
            float v0=f0.x*rn, v1=f0.y*rn, v2=f1.x*rn, v3=f1.y*rn;
            float v4=f2.x*rn, v5=f2.y*rn, v6=f3.x*rn, v7=f3.y*rn;
            f32x4 o0, o1;
            o0[0] = v0 > 0.f ? v0 : expm1f(v0);
            o0[1] = v1 > 0.f ? v1 : expm1f(v1);
            o0[2] = v2 > 0.f ? v2 : expm1f(v2);
            o0[3] = v3 > 0.f ? v3 : expm1f(v3);
            o1[0] = v4 > 0.f ? v4 : expm1f(v4);
            o1[1] = v5 > 0.f ? v5 : expm1f(v5);
            o1[2] = v6 > 0.f ? v6 : expm1f(v6);
            o1[3] = v7 > 0.f ? v7 : expm1f(v7);
            float* obase = out + (size_t)t * NN * IND + ((size_t)node << 7) + (dl3 << 3);
            float* obase2 = obase + (size_t)NT * NN * IND;
            __builtin_nontemporal_store(o0, reinterpret_cast<f32x4*>(obase));
            __builtin_nontemporal_store(o1, reinterpret_cast<f32x4*>(obase + 4));
            __builtin_nontemporal_store(o0, reinterpret_cast<f32x4*>(obase2));
            __builtin_nontemporal_store(o1, reinterpret_cast<f32x4*>(obase2 + 4));
        }
    }
}

extern "C" void kernel_launch(void* const* d_in, const int* in_sizes, int n_in,
                              void* d_out, int out_size, void* d_ws, size_t ws_size,
                              hipStream_t stream)
{
    const float* x     = (const float*)d_in[0];
    const int*   edges = (const int*)d_in[1];
    const float* W     = (const float*)d_in[2];
    const float* asrc  = (const float*)d_in[3];
    const float* adst  = (const float*)d_in[4];
    float* out = (float*)d_out;

    char* p = (char*)d_ws;
    __half*   h16      = (__half*)p;   p += (size_t)NT * NN * IND * 2;            // 38.4 MB
    float*    es       = (float*)p;    p += (size_t)NT * NN * NH * 4;             // 2.4 MB
    float*    ed       = (float*)p;    p += (size_t)NT * NN * NH * 4;             // 2.4 MB
    int*      gcursor  = (int*)p;      p += (size_t)NBTOT * 4;
    __half*   wt16g    = (__half*)p;   p += (size_t)NT * IND * IND * 2;           // 96 KB
    unsigned* bucketed = (unsigned*)p; p += ((size_t)NBTOT * BCAP + 1024) * 4;    // 12 MB

    prep_kernel<<<(NT * IND * IND + 255) / 256, 256, 0, stream>>>(W, wt16g, gcursor);
    scatter_gemm_kernel<<<SCB + NT * GXB, 512, 0, stream>>>(
        edges, gcursor, bucketed, x, wt16g, asrc, adst, h16, es, ed);
    gat_bucket_kernel<<<NBTOT, 512, 0, stream>>>(bucketed, gcursor, es, ed, h16, out);
}

// Round 16
// 201.510 us; speedup vs baseline: 1.0771x; 1.0771x over previous
//
#include <hip/hip_runtime.h>
#include <hip/hip_fp16.h>
#include <math.h>

#define NN 50000
#define IND 128
#define NH 4
#define NE 800000
#define NT 3
#define NSLOPE 0.2f

#define TILE 48                    // dsts per bucket
#define NBPT 1042                  // ceil(NN/TILE)
#define NBTOT (NT * NBPT)          // 3126
#define BCAP 960                   // slots per bucket (mean 768, +6.9 sigma)
#define SRTCAP (BCAP + 3 * TILE)   // 1104: sorted + per-dst pad-to-4 dummies
#define DUMMY 0xFFFFu

#define SEB 8192                        // edges per scatter block (r15's 32768 serialized; revert)
#define SCB ((NT * NE + SEB - 1) / SEB) // 293 scatter blocks
#define GXB ((NN + 127) / 128)          // 391 gemm blocks per type

typedef _Float16 f16x8 __attribute__((ext_vector_type(8)));
typedef float    f32x4 __attribute__((ext_vector_type(4)));

__device__ __forceinline__ unsigned pk_add_f16(unsigned a, unsigned b) {
    __half2 x = *reinterpret_cast<__half2*>(&a);
    __half2 y = *reinterpret_cast<__half2*>(&b);
    __half2 r = __hadd2(x, y);
    return *reinterpret_cast<unsigned*>(&r);
}

// ---------------- prep: W^T fp16 + gcursor init ----------------
__global__ __launch_bounds__(256) void prep_kernel(
    const float* __restrict__ W, __half* __restrict__ wt16g, int* __restrict__ gcursor)
{
    int idx = blockIdx.x * 256 + threadIdx.x;
    if (idx < NT * IND * IND) {
        int t = idx / (IND * IND), r = idx - t * (IND * IND);
        int k = r >> 7, c = r & 127;
        wt16g[((size_t)t * IND + c) * IND + k] = (__half)W[idx];   // wt16g[t][c][k]
    }
    if (idx < NBTOT) gcursor[idx] = idx * BCAP;
}

// ---------------- combined: bucket_scatter (blocks 0..SCB-1) + MFMA GEMM ----------------
__global__ __launch_bounds__(512) void scatter_gemm_kernel(
    const int* __restrict__ edges, int* __restrict__ gcursor, unsigned* __restrict__ bucketed,
    const float* __restrict__ x, const __half* __restrict__ wt16g,
    const float* __restrict__ asrc, const float* __restrict__ adst,
    __half* __restrict__ h16, float* __restrict__ es, float* __restrict__ ed)
{
    __shared__ __align__(16) char ldsbuf[34816];
    const int tid = threadIdx.x;

    if (blockIdx.x < SCB) {
        // ---- bucket scatter: SEB edges/block ----
        int* cnt = (int*)ldsbuf;                 // NBTOT ints
        int* bas = cnt + NBTOT;                  // NBTOT ints (25.0 KB total)
        for (int i = tid; i < NBTOT; i += 512) cnt[i] = 0;
        __syncthreads();
        const long long gtot = (long long)NT * NE;
        const long long g0 = (long long)blockIdx.x * SEB;
        long long g1 = g0 + SEB; if (g1 > gtot) g1 = gtot;
        for (long long g = g0 + tid; g < g1; g += 512) {
            int t = (g >= 2LL * NE) ? 2 : (g >= NE ? 1 : 0);
            int e = (int)(g - (long long)t * NE);
            int d = edges[(size_t)t * 2 * NE + NE + e];
            atomicAdd(&cnt[t * NBPT + d / TILE], 1);
        }
        __syncthreads();
        for (int i = tid; i < NBTOT; i += 512) {
            int c = cnt[i];
            bas[i] = c ? atomicAdd(&gcursor[i], c) : 0;
            cnt[i] = 0;
        }
        __syncthreads();
        for (long long g = g0 + tid; g < g1; g += 512) {
            int t = (g >= 2LL * NE) ? 2 : (g >= NE ? 1 : 0);
            int e = (int)(g - (long long)t * NE);
            const int* eb = edges + (size_t)t * 2 * NE;
            int s = eb[e], d = eb[NE + e];
            int bkt = d / TILE;
            int bg = t * NBPT + bkt;
            int pos = bas[bg] + atomicAdd(&cnt[bg], 1);
            bucketed[pos] = (unsigned)s | ((unsigned)(d - bkt * TILE) << 16);
        }
        return;
    }

    // ---- MFMA GEMM: 8 waves x 16 rows = 128 rows/block ----
    const int bx = blockIdx.x - SCB;
    const int t  = bx / GXB;
    const int gx = bx - t * GXB;
    __half* tile = (__half*)ldsbuf;
    const int wid = tid >> 6, lane = tid & 63;
    __half* tl = tile + wid * (16 * 136);
    const int l15 = lane & 15, l4 = lane >> 4;
    const int r0 = gx * 128 + wid * 16;
    if (r0 >= NN) return;                    // NN%16==0 -> wave-uniform

    const __half* wt = wt16g + (size_t)t * IND * IND;
    const float* xrow = x + (size_t)(r0 + l15) * IND;

    f32x4 acc[8];
    #pragma unroll
    for (int i = 0; i < 8; i++) acc[i] = (f32x4){0.f, 0.f, 0.f, 0.f};

    #pragma unroll
    for (int ks = 0; ks < 4; ks++) {
        const int kb = ks * 32 + l4 * 8;
        float4 x0 = *reinterpret_cast<const float4*>(xrow + kb);
        float4 x1 = *reinterpret_cast<const float4*>(xrow + kb + 4);
        f16x8 af;
        af[0] = (_Float16)x0.x; af[1] = (_Float16)x0.y;
        af[2] = (_Float16)x0.z; af[3] = (_Float16)x0.w;
        af[4] = (_Float16)x1.x; af[5] = (_Float16)x1.y;
        af[6] = (_Float16)x1.z; af[7] = (_Float16)x1.w;
        #pragma unroll
        for (int ct = 0; ct < 8; ct++) {
            f16x8 bf = *reinterpret_cast<const f16x8*>(wt + (size_t)(ct * 16 + l15) * IND + kb);
            acc[ct] = __builtin_amdgcn_mfma_f32_16x16x32_f16(af, bf, acc[ct], 0, 0, 0);
        }
    }

    #pragma unroll
    for (int ct = 0; ct < 8; ct++)
        #pragma unroll
        for (int r = 0; r < 4; r++)
            tl[(l4 * 4 + r) * 136 + ct * 16 + l15] = (__half)acc[ct][r];
    __syncthreads();

    {
        #pragma unroll
        for (int i = 0; i < 4; i++) {        // 256 x 16B chunks: full 16x128 tile
            int c = lane + 64 * i;
            int row = c >> 4, off = (c & 15) * 8;
            f16x8 v = *reinterpret_cast<const f16x8*>(tl + row * 136 + off);
            *reinterpret_cast<f16x8*>(h16 + ((size_t)t * NN + r0 + row) * IND + off) = v;
        }
        int row16 = lane >> 2, head = lane & 3;
        const __half* hr = tl + row16 * 136 + head * 32;
        const float* av = asrc + ((size_t)t * NH + head) * 32;
        const float* bv = adst + ((size_t)t * NH + head) * 32;
        float se = 0.f, de = 0.f;
        #pragma unroll
        for (int jj = 0; jj < 4; jj++) {
            f16x8 hv = *reinterpret_cast<const f16x8*>(hr + jj * 8);
            #pragma unroll
            for (int j = 0; j < 8; j++) {
                float hf = (float)hv[j];
                se = fmaf(hf, av[jj * 8 + j], se);
                de = fmaf(hf, bv[jj * 8 + j], de);
            }
        }
        int n = r0 + row16;
        es[((size_t)t * NN + n) * NH + head] = se;
        ed[((size_t)t * NN + n) * NH + head] = de;
    }
}

// ---------------- per-bucket: LDS sort (pad-to-4 w/ DUMMY) -> fused GAT ----------------
// 512 thr = 8 waves; wave w handles dsts w*6..w*6+5. Inner: quarter-wave 4-edge steps,
// GUARD-FREE (lists padded to x4; sentinel edges carry w=0, sv=0). Packed f16 accum.
// Shuffles UNCONDITIONAL (exec-mask rule).
__global__ __launch_bounds__(512) void gat_bucket_kernel(
    const unsigned* __restrict__ bucketed, const int* __restrict__ gcursor,
    const float* __restrict__ es, const float* __restrict__ ed,
    const __half* __restrict__ h16, float* __restrict__ out)
{
    __shared__ unsigned pk[BCAP];
    __shared__ unsigned srt[SRTCAP];
    __shared__ int hist[64], scn[64], cur[64];
    const int bg = blockIdx.x;
    const int t = bg / NBPT;
    const int node0 = (bg - t * NBPT) * TILE;
    const int tid = threadIdx.x;
    const int base = bg * BCAP;
    const int cnt = gcursor[bg] - base;

    if (tid < 64) { hist[tid] = 0; cur[tid] = 0; }
    __syncthreads();
    for (int i = tid; i < cnt; i += 512) {
        unsigned v = __builtin_nontemporal_load(&bucketed[base + i]);
        pk[i] = v;
        atomicAdd(&hist[(v >> 16) & 63u], 1);
    }
    __syncthreads();
    if (tid < 64) {                        // exclusive scan over PADDED counts
        int v = hist[tid];
        int v4 = (v + 3) & ~3;
        int inc = v4;
        #pragma unroll
        for (int off = 1; off < 64; off <<= 1) {
            int n = __shfl_up(inc, off, 64);
            if (tid >= off) inc += n;
        }
        scn[tid] = inc - v4;
    }
    __syncthreads();
    for (int i = tid; i < cnt; i += 512) {
        unsigned v = pk[i];
        int dl = (int)((v >> 16) & 63u);
        int pos = scn[dl] + atomicAdd(&cur[dl], 1);
        srt[pos] = v & 0xFFFFu;
    }
    if (tid < 64) {                        // pad each dst run to x4 with DUMMY
        int h = hist[tid], h4 = (h + 3) & ~3, b = scn[tid];
        for (int i = h; i < h4; i++) srt[b + i] = DUMMY;
    }
    __syncthreads();

    const int wid = tid >> 6, lane = tid & 63;
    const int el2 = lane >> 4;         // quarter index: edge offset within 4-edge step
    const int dl3 = lane & 15;         // dims 8*dl3 .. 8*dl3+7
    const int hsel = dl3 >> 2;         // head of this lane's dims
    const float* es_t = es + (size_t)t * NN * NH;
    const __half* h16_t = h16 + (size_t)t * NN * IND;

    for (int j = 0; j < 6; j++) {
        const int dloc = wid * 6 + j;
        const int node = node0 + dloc;
        if (node >= NN) break;
        const int beg = scn[dloc];
        const int nE = (hist[dloc] + 3) & ~3;      // padded count
        const float edv = ed[((size_t)t * NN + node) * NH + (lane & 3)];

        unsigned p0 = 0u, p1 = 0u, p2 = 0u, p3 = 0u;   // packed f16 accum (8 dims)
        float dsum = 0.f;

        for (int b2 = 0; b2 < nE; b2 += 16) {
            int ne = nE - b2; if (ne > 16) ne = 16;    // multiple of 4
            const int ei = lane >> 2;
            int sv = 0; unsigned wpk = 0u;
            if (ei < ne) {
                unsigned svr = srt[beg + b2 + ei];
                if (svr != DUMMY) {
                    float s = es_t[(svr << 2) + (lane & 3)] + edv;
                    s = s > 0.f ? s : NSLOPE * s;
                    float wv = __expf(s);
                    dsum += wv;
                    __half2 w2 = __float2half2_rn(wv);
                    wpk = *reinterpret_cast<unsigned*>(&w2);
                    sv = (int)svr;
                }
            }
            for (int kk = 0; kk < ne; kk += 4) {       // GUARD-FREE steps
                int sl = (kk + el2) << 2;
                int      sb = __shfl(sv, sl, 64);
                unsigned wb = (unsigned)__shfl((int)wpk, sl | hsel, 64);
                uint4 hv = *reinterpret_cast<const uint4*>(h16_t + ((size_t)sb << 7) + (dl3 << 3));
                asm("v_pk_fma_f16 %0, %1, %2, %0" : "+v"(p0) : "v"(hv.x), "v"(wb));
                asm("v_pk_fma_f16 %0, %1, %2, %0" : "+v"(p1) : "v"(hv.y), "v"(wb));
                asm("v_pk_fma_f16 %0, %1, %2, %0" : "+v"(p2) : "v"(hv.z), "v"(wb));
                asm("v_pk_fma_f16 %0, %1, %2, %0" : "+v"(p3) : "v"(hv.w), "v"(wb));
            }
        }

        // dsum: sum over edge-slots (bits 2..5), head = lane&3
        #pragma unroll
        for (int m = 4; m <= 32; m <<= 1) dsum += __shfl_xor(dsum, m, 64);
        // acc: packed f16 adds across quarters (same dl3)
        #pragma unroll
        for (int m = 16; m <= 32; m <<= 1) {
            p0 = pk_add_f16(p0, (unsigned)__shfl_xor((int)p0, m, 64));
            p1 = pk_add_f16(p1, (unsigned)__shfl_xor((int)p1, m, 64));
            p2 = pk_add_f16(p2, (unsigned)__shfl_xor((int)p2, m, 64));
            p3 = pk_add_f16(p3, (unsigned)__shfl_xor((int)p3, m, 64));
        }
        float dn = __shfl(dsum, hsel, 64) + 1e-9f;

        if (el2 == 0) {
            float rn = 1.f / dn;
            float2 f0 = __half22float2(*reinterpret_cast<__half2*>(&p0));
            float2 f1 = __half22float2(*reinterpret_cast<__half2*>(&p1));
            float2 f2 = __half22float2(*reinterpret_cast<__half2*>(&p2));
            float2 f3 = __half22float2(*reinterpret_cast<__half2*>(&p3));
            float v0=f0.x*rn, v1=f0.y*rn, v2=f1.x*rn, v3=f1.y*rn;
            float v4=f2.x*rn, v5=f2.y*rn, v6=f3.x*rn, v7=f3.y*rn;
            f32x4 o0, o1;
            o0[0] = v0 > 0.f ? v0 : expm1f(v0);
            o0[1] = v1 > 0.f ? v1 : expm1f(v1);
            o0[2] = v2 > 0.f ? v2 : expm1f(v2);
            o0[3] = v3 > 0.f ? v3 : expm1f(v3);
            o1[0] = v4 > 0.f ? v4 : expm1f(v4);
            o1[1] = v5 > 0.f ? v5 : expm1f(v5);
            o1[2] = v6 > 0.f ? v6 : expm1f(v6);
            o1[3] = v7 > 0.f ? v7 : expm1f(v7);
            float* obase = out + (size_t)t * NN * IND + ((size_t)node << 7) + (dl3 << 3);
            float* obase2 = obase + (size_t)NT * NN * IND;
            __builtin_nontemporal_store(o0, reinterpret_cast<f32x4*>(obase));
            __builtin_nontemporal_store(o1, reinterpret_cast<f32x4*>(obase + 4));
            __builtin_nontemporal_store(o0, reinterpret_cast<f32x4*>(obase2));
            __builtin_nontemporal_store(o1, reinterpret_cast<f32x4*>(obase2 + 4));
        }
    }
}

extern "C" void kernel_launch(void* const* d_in, const int* in_sizes, int n_in,
                              void* d_out, int out_size, void* d_ws, size_t ws_size,
                              hipStream_t stream)
{
    const float* x     = (const float*)d_in[0];
    const int*   edges = (const int*)d_in[1];
    const float* W     = (const float*)d_in[2];
    const float* asrc  = (const float*)d_in[3];
    const float* adst  = (const float*)d_in[4];
    float* out = (float*)d_out;

    char* p = (char*)d_ws;
    __half*   h16      = (__half*)p;   p += (size_t)NT * NN * IND * 2;            // 38.4 MB
    float*    es       = (float*)p;    p += (size_t)NT * NN * NH * 4;             // 2.4 MB
    float*    ed       = (float*)p;    p += (size_t)NT * NN * NH * 4;             // 2.4 MB
    int*      gcursor  = (int*)p;      p += (size_t)NBTOT * 4;
    __half*   wt16g    = (__half*)p;   p += (size_t)NT * IND * IND * 2;           // 96 KB
    unsigned* bucketed = (unsigned*)p; p += ((size_t)NBTOT * BCAP + 1024) * 4;    // 12 MB

    prep_kernel<<<(NT * IND * IND + 255) / 256, 256, 0, stream>>>(W, wt16g, gcursor);
    scatter_gemm_kernel<<<SCB + NT * GXB, 512, 0, stream>>>(
        edges, gcursor, bucketed, x, wt16g, asrc, adst, h16, es, ed);
    gat_bucket_kernel<<<NBTOT, 512, 0, stream>>>(bucketed, gcursor, es, ed, h16, out);
}